// Round 11
// baseline (71.899 us; speedup 1.0000x reference)
//
#include <hip/hip_runtime.h>
#include <math.h>

#define NCLUS 64
#define BLOCK 256
#define GC 512               // cluster_sums grid (fixed; one slot per block)
#define FP_FIELDS 320        // 5 fields * 64 clusters per slot

#if __has_builtin(__builtin_amdgcn_exp2f)
#define EXP2F(x) __builtin_amdgcn_exp2f(x)
#else
#define EXP2F(x) __expf(0.6931471805599453f * (x))
#endif

// softplus(p)=log(1+e^p) on [0,1] ~= Q0 + Q1*p + Q2*p^2, max err ~6e-4
// (irrelevant vs threshold). Q0 hoisted; added back at finalize as n*64*Q0.
#define SPQ0 0.692941
#define SPQ1 0.503668f
#define SPQ2 0.117225f

// ws layout:
//  [0, 655360):        float slots[GC][320]  per-block cluster partials,
//                      idx = field*64+c, field: 0=count 1=sx 2=sy 3=sz 4=margin
//  [655360, 656896):   float P[384]: [0,256) float4(ax,ay,az,b), [256,320) w2,
//                      [320,384) sigma
//  [657408, ...):      float pb[grid*3]  per-block partials (bce,seed,smooth)
// No init kernel: every slot/pb element is unconditionally rewritten each call.

__global__ __launch_bounds__(BLOCK) void cluster_sums_kernel(
        const float* __restrict__ coords, const float* __restrict__ margins,
        const int* __restrict__ labels, int n, float* __restrict__ slots) {
    __shared__ float s_h[8][5][65];   // 8 LDS replicas, padded rows
    for (int i = threadIdx.x; i < 8 * 5 * 65; i += BLOCK)
        ((float*)s_h)[i] = 0.0f;
    __syncthreads();

    const int rep = threadIdx.x & 7;
    const int np = n >> 1;
    const int stride = gridDim.x * BLOCK;
    const float2* c2 = (const float2*)coords;
    const float2* m2 = (const float2*)margins;
    const int2* l2 = (const int2*)labels;

    for (int i = blockIdx.x * BLOCK + threadIdx.x; i < np; i += stride) {
        float2 a0 = c2[i * 3], a1 = c2[i * 3 + 1], a2 = c2[i * 3 + 2];
        float2 mg = m2[i];
        int2 lb = l2[i];
        // point 0: (a0.x, a0.y, a1.x), point 1: (a1.y, a2.x, a2.y)
        atomicAdd(&s_h[rep][0][lb.x], 1.0f);
        atomicAdd(&s_h[rep][1][lb.x], a0.x);
        atomicAdd(&s_h[rep][2][lb.x], a0.y);
        atomicAdd(&s_h[rep][3][lb.x], a1.x);
        atomicAdd(&s_h[rep][4][lb.x], mg.x);
        atomicAdd(&s_h[rep][0][lb.y], 1.0f);
        atomicAdd(&s_h[rep][1][lb.y], a1.y);
        atomicAdd(&s_h[rep][2][lb.y], a2.x);
        atomicAdd(&s_h[rep][3][lb.y], a2.y);
        atomicAdd(&s_h[rep][4][lb.y], mg.y);
    }
    // odd-n tail
    if ((n & 1) && blockIdx.x == 0 && threadIdx.x == 0) {
        int p = n - 1;
        int lab = labels[p];
        atomicAdd(&s_h[rep][0][lab], 1.0f);
        atomicAdd(&s_h[rep][1][lab], coords[p * 3 + 0]);
        atomicAdd(&s_h[rep][2][lab], coords[p * 3 + 1]);
        atomicAdd(&s_h[rep][3][lab], coords[p * 3 + 2]);
        atomicAdd(&s_h[rep][4][lab], margins[p]);
    }
    __syncthreads();

    // flush: plain coalesced stores to this block's private slot (no atomics)
    float* slot = slots + blockIdx.x * FP_FIELDS;
    for (int idx = threadIdx.x; idx < FP_FIELDS; idx += BLOCK) {
        int field = idx >> 6, c = idx & 63;
        float v = 0.0f;
#pragma unroll
        for (int r = 0; r < 8; ++r) v += s_h[r][field][c];
        slot[idx] = v;
    }
}

// 1 block x 512 threads: reduce nb slots -> params P[384]
__global__ __launch_bounds__(512) void compute_params_kernel(
        const float* __restrict__ slots, int nb, float* __restrict__ P) {
    __shared__ float s_p[8][5][64];
    const int c = threadIdx.x & 63;
    const int g = threadIdx.x >> 6;   // 8 groups of 64

    float acc[5] = {0.f, 0.f, 0.f, 0.f, 0.f};
    for (int b = g; b < nb; b += 8) {
        const float* slot = slots + b * FP_FIELDS;
#pragma unroll
        for (int f = 0; f < 5; ++f) acc[f] += slot[f * 64 + c];
    }
#pragma unroll
    for (int f = 0; f < 5; ++f) s_p[g][f][c] = acc[f];
    __syncthreads();

    if (threadIdx.x < NCLUS) {
        float cnt = 0.f, sx = 0.f, sy = 0.f, sz = 0.f, sm = 0.f;
#pragma unroll
        for (int r = 0; r < 8; ++r) {
            cnt += s_p[r][0][c]; sx += s_p[r][1][c]; sy += s_p[r][2][c];
            sz += s_p[r][3][c]; sm += s_p[r][4][c];
        }
        float inv = 1.0f / cnt;
        float sig = sm * inv;
        float cx = sx * inv, cy = sy * inv, cz = sz * inv;
        float w2 = -1.4426950408889634f / (2.0f * sig * sig);
        ((float4*)P)[c] = make_float4(-2.0f * w2 * cx, -2.0f * w2 * cy,
                                      -2.0f * w2 * cz,
                                      w2 * fmaf(cx, cx, fmaf(cy, cy, cz * cz)));
        P[256 + c] = w2;
        P[320 + c] = sig;
    }
}

// returns block sum on thread 0 only
__device__ __forceinline__ float block_reduce_f(float v, float* s_red) {
    for (int o = 32; o > 0; o >>= 1) v += __shfl_down(v, o);
    int lane = threadIdx.x & 63, wid = threadIdx.x >> 6;
    __syncthreads();
    if (lane == 0) s_red[wid] = v;
    __syncthreads();
    float t = 0.0f;
    if (threadIdx.x == 0)
        for (int w = 0; w < BLOCK / 64; ++w) t += s_red[w];
    return t;
}

// 2 points/thread, exact grid, params broadcast from LDS (proven R9 shape)
__global__ __launch_bounds__(BLOCK, 8) void main_loss_kernel(
        const float* __restrict__ emb, const float* __restrict__ margins,
        const float* __restrict__ seed, const int* __restrict__ labels,
        int n, const float* __restrict__ P, float* __restrict__ pb) {
    __shared__ float4 s_par[NCLUS];   // ax,ay,az,b
    __shared__ float s_w[NCLUS];
    __shared__ float s_sig[NCLUS];
    __shared__ float s_red[BLOCK / 64];

    if (threadIdx.x < NCLUS) {
        int c = threadIdx.x;
        s_par[c] = ((const float4*)P)[c];
        s_w[c] = P[256 + c];
        s_sig[c] = P[320 + c];
    }
    __syncthreads();

    const int np = n >> 1;
    const int i = blockIdx.x * BLOCK + threadIdx.x;  // pair index

    float bce = 0.0f, seed_s = 0.0f, smooth_s = 0.0f;

    if (i < np) {
        const float2* e2 = (const float2*)emb;
        float2 a0 = e2[i * 3], a1 = e2[i * 3 + 1], a2 = e2[i * 3 + 2];
        float2 mg = ((const float2*)margins)[i];
        float2 sv = ((const float2*)seed)[i];
        int2 lb = ((const int2*)labels)[i];

        float x[2] = {a0.x, a1.y};
        float y[2] = {a0.y, a2.x};
        float z[2] = {a1.x, a2.y};
        float es[2], a[2] = {0.f, 0.f};
#pragma unroll
        for (int k = 0; k < 2; ++k)
            es[k] = fmaf(x[k], x[k], fmaf(y[k], y[k], z[k] * z[k]));

#pragma unroll 8
        for (int c = 0; c < NCLUS; ++c) {
            float4 pr = s_par[c];
            float w2 = s_w[c];
#pragma unroll
            for (int k = 0; k < 2; ++k) {
                float t = fmaf(pr.x, x[k], fmaf(pr.y, y[k],
                          fmaf(pr.z, z[k], fmaf(w2, es[k], pr.w))));
                float p = EXP2F(t);
                a[k] = fmaf(p, fmaf(p, SPQ2, SPQ1), a[k]);
            }
        }
        bce += a[0] + a[1];

        float mm[2] = {mg.x, mg.y};
        float ss[2] = {sv.x, sv.y};
        int   ll[2] = {lb.x, lb.y};
#pragma unroll
        for (int k = 0; k < 2; ++k) {
            float4 pr = s_par[ll[k]];
            float w2 = s_w[ll[k]];
            float t = fmaf(pr.x, x[k], fmaf(pr.y, y[k],
                      fmaf(pr.z, z[k], fmaf(w2, es[k], pr.w))));
            float p = EXP2F(t);
            bce -= p;
            seed_s += fabsf(p - ss[k]);
            float dg = mm[k] - s_sig[ll[k]];
            smooth_s += dg * dg;
        }
    }
    // odd-n tail
    if ((n & 1) && blockIdx.x == 0 && threadIdx.x == 0) {
        int p = n - 1;
        float ex = emb[p * 3 + 0], ey = emb[p * 3 + 1], ez = emb[p * 3 + 2];
        float esq = fmaf(ex, ex, fmaf(ey, ey, ez * ez));
        int lab = labels[p];
        float pl = 0.0f;
        for (int c = 0; c < NCLUS; ++c) {
            float4 pr = s_par[c];
            float w2 = s_w[c];
            float t = fmaf(pr.x, ex, fmaf(pr.y, ey, fmaf(pr.z, ez, fmaf(w2, esq, pr.w))));
            float p2 = EXP2F(t);
            pl = (c == lab) ? p2 : pl;
            bce = fmaf(p2, fmaf(p2, SPQ2, SPQ1), bce);
        }
        bce -= pl;
        seed_s += fabsf(pl - seed[p]);
        float dg = margins[p] - s_sig[lab];
        smooth_s += dg * dg;
    }

    float r;
    r = block_reduce_f(bce, s_red);
    if (threadIdx.x == 0) pb[blockIdx.x * 3 + 0] = r;
    r = block_reduce_f(seed_s, s_red);
    if (threadIdx.x == 0) pb[blockIdx.x * 3 + 1] = r;
    r = block_reduce_f(smooth_s, s_red);
    if (threadIdx.x == 0) pb[blockIdx.x * 3 + 2] = r;
}

__global__ void finalize_kernel(const float* __restrict__ pb, int nb,
                                float* __restrict__ out, int n) {
    __shared__ float s_red[BLOCK / 64];
    float v0 = 0.f, v1 = 0.f, v2 = 0.f;
    for (int j = threadIdx.x; j < nb; j += BLOCK) {
        v0 += pb[j * 3 + 0];
        v1 += pb[j * 3 + 1];
        v2 += pb[j * 3 + 2];
    }
    float t0 = block_reduce_f(v0, s_red);
    __syncthreads();
    float t1 = block_reduce_f(v1, s_red);
    __syncthreads();
    float t2 = block_reduce_f(v2, s_red);
    if (threadIdx.x == 0) {
        double bce_total = (double)t0 + (double)n * 64.0 * SPQ0;
        out[0] = (float)(bce_total / ((double)NCLUS * (double)n)
                         + (double)t1 / (double)n + (double)t2 / (double)NCLUS);
    }
}

extern "C" void kernel_launch(void* const* d_in, const int* in_sizes, int n_in,
                              void* d_out, int out_size, void* d_ws, size_t ws_size,
                              hipStream_t stream) {
    const float* emb     = (const float*)d_in[0];
    const float* margins = (const float*)d_in[1];
    const float* seed    = (const float*)d_in[2];
    const float* coords  = (const float*)d_in[3];
    const int*   labels  = (const int*)d_in[4];
    int n = in_sizes[4];

    float* slots = (float*)d_ws;
    float* P  = (float*)((char*)d_ws + 655360);
    float* pb = (float*)((char*)d_ws + 657408);
    float* out = (float*)d_out;

    int np = n >> 1;
    int grid_main = (np + BLOCK - 1) / BLOCK;
    if (grid_main < 1) grid_main = 1;
    int grid_cs = grid_main < GC ? grid_main : GC;

    cluster_sums_kernel<<<grid_cs, BLOCK, 0, stream>>>(coords, margins, labels, n, slots);
    compute_params_kernel<<<1, 512, 0, stream>>>(slots, grid_cs, P);
    main_loss_kernel<<<grid_main, BLOCK, 0, stream>>>(emb, margins, seed, labels, n, P, pb);
    finalize_kernel<<<1, BLOCK, 0, stream>>>(pb, grid_main, out, n);
}

// Round 12
// 58.745 us; speedup vs baseline: 1.2239x; 1.2239x over previous
//
#include <hip/hip_runtime.h>
#include <math.h>

#define NCLUS 64
#define BLOCK 256
#define GC 512               // cluster_sums grid (grid-stride)
#define NREP 8               // global S replicas to spread atomic contention
#define FP_SCALE 1048576.0f  // 2^20 fixed-point scale for cluster sums

#if __has_builtin(__builtin_amdgcn_exp2f)
#define EXP2F(x) __builtin_amdgcn_exp2f(x)
#else
#define EXP2F(x) __expf(0.6931471805599453f * (x))
#endif

// softplus(p)=log(1+e^p) on [0,1] ~= Q0 + Q1*p + Q2*p^2, max err ~6e-4
// (irrelevant vs threshold). Q0 hoisted; added back at finalize as n*64*Q0.
#define SPQ0 0.692941
#define SPQ1 0.503668f
#define SPQ2 0.117225f

// ws layout:
//  [0, 20480):   u64 S8[8][320]  fixed-point cluster sums, idx = field*64+c
//                field: 0=count 1=sx 2=sy 3=sz 4=margin; replica = blockIdx&7
//  [24576, ...): float pb[grid*3]  per-block partials (bce,seed,smooth)

__global__ void init_ws_kernel(unsigned long long* S8) {
    int i = blockIdx.x * blockDim.x + threadIdx.x;
    if (i < NREP * 5 * NCLUS) S8[i] = 0ULL;
}

__global__ __launch_bounds__(BLOCK) void cluster_sums_kernel(
        const float* __restrict__ coords, const float* __restrict__ margins,
        const int* __restrict__ labels, int n, unsigned long long* __restrict__ S8) {
    __shared__ float s_h[8][5][65];   // 8 LDS replicas, padded rows
    for (int i = threadIdx.x; i < 8 * 5 * 65; i += BLOCK)
        ((float*)s_h)[i] = 0.0f;
    __syncthreads();

    const int rep = threadIdx.x & 7;
    const int np = n >> 1;
    const int stride = gridDim.x * BLOCK;
    const float2* c2 = (const float2*)coords;
    const float2* m2 = (const float2*)margins;
    const int2* l2 = (const int2*)labels;

    for (int i = blockIdx.x * BLOCK + threadIdx.x; i < np; i += stride) {
        float2 a0 = c2[i * 3], a1 = c2[i * 3 + 1], a2 = c2[i * 3 + 2];
        float2 mg = m2[i];
        int2 lb = l2[i];
        // point 0: (a0.x, a0.y, a1.x), point 1: (a1.y, a2.x, a2.y)
        atomicAdd(&s_h[rep][0][lb.x], 1.0f);
        atomicAdd(&s_h[rep][1][lb.x], a0.x);
        atomicAdd(&s_h[rep][2][lb.x], a0.y);
        atomicAdd(&s_h[rep][3][lb.x], a1.x);
        atomicAdd(&s_h[rep][4][lb.x], mg.x);
        atomicAdd(&s_h[rep][0][lb.y], 1.0f);
        atomicAdd(&s_h[rep][1][lb.y], a1.y);
        atomicAdd(&s_h[rep][2][lb.y], a2.x);
        atomicAdd(&s_h[rep][3][lb.y], a2.y);
        atomicAdd(&s_h[rep][4][lb.y], mg.y);
    }
    // odd-n tail
    if ((n & 1) && blockIdx.x == 0 && threadIdx.x == 0) {
        int p = n - 1;
        int lab = labels[p];
        atomicAdd(&s_h[rep][0][lab], 1.0f);
        atomicAdd(&s_h[rep][1][lab], coords[p * 3 + 0]);
        atomicAdd(&s_h[rep][2][lab], coords[p * 3 + 1]);
        atomicAdd(&s_h[rep][3][lab], coords[p * 3 + 2]);
        atomicAdd(&s_h[rep][4][lab], margins[p]);
    }
    __syncthreads();

    // flush to this block's global replica (u64 fixed-point, native int atomics)
    unsigned long long* Sr = S8 + (blockIdx.x & (NREP - 1)) * 5 * NCLUS;
    for (int idx = threadIdx.x; idx < 5 * NCLUS; idx += BLOCK) {
        int field = idx >> 6, c = idx & 63;
        float v = 0.0f;
#pragma unroll
        for (int r = 0; r < 8; ++r) v += s_h[r][field][c];
        unsigned long long q = (unsigned long long)(long long)llrintf(v * FP_SCALE);
        if (q) atomicAdd(&Sr[idx], q);
    }
}

// returns block sum on thread 0 only
__device__ __forceinline__ float block_reduce_f(float v, float* s_red) {
    for (int o = 32; o > 0; o >>= 1) v += __shfl_down(v, o);
    int lane = threadIdx.x & 63, wid = threadIdx.x >> 6;
    __syncthreads();
    if (lane == 0) s_red[wid] = v;
    __syncthreads();
    float t = 0.0f;
    if (threadIdx.x == 0)
        for (int w = 0; w < BLOCK / 64; ++w) t += s_red[w];
    return t;
}

// 2 points/thread, exact grid; params in LDS, w2 packed 4-wide so each
// 4-cluster group costs 5 ds_read_b128 (was 4x b128 + 4x b32): -37% LDS instrs.
__global__ __launch_bounds__(BLOCK, 8) void main_loss_kernel(
        const float* __restrict__ emb, const float* __restrict__ margins,
        const float* __restrict__ seed, const int* __restrict__ labels,
        int n, const unsigned long long* __restrict__ S8,
        float* __restrict__ pb) {
    __shared__ float4 s_par[NCLUS];      // ax,ay,az,b
    __shared__ float4 s_w4[NCLUS / 4];   // w2 packed 4-wide
    __shared__ float s_sig[NCLUS];
    __shared__ float s_red[BLOCK / 64];

    // ---- params: sum NREP replicas, all-float after (2^20 scale cancels) ----
    if (threadIdx.x < NCLUS) {
        int c = threadIdx.x;
        long long acc[5] = {0, 0, 0, 0, 0};
#pragma unroll
        for (int r = 0; r < NREP; ++r) {
#pragma unroll
            for (int f = 0; f < 5; ++f)
                acc[f] += (long long)S8[r * 5 * NCLUS + f * NCLUS + c];
        }
        float cnt = (float)acc[0];
        float sx = (float)acc[1], sy = (float)acc[2], sz = (float)acc[3];
        float sm = (float)acc[4];
        float inv = 1.0f / cnt;
        float sig = sm * inv;
        float cx = sx * inv, cy = sy * inv, cz = sz * inv;
        float w2 = -1.4426950408889634f / (2.0f * sig * sig);
        s_par[c] = make_float4(-2.0f * w2 * cx, -2.0f * w2 * cy, -2.0f * w2 * cz,
                               w2 * fmaf(cx, cx, fmaf(cy, cy, cz * cz)));
        ((float*)s_w4)[c] = w2;
        s_sig[c] = sig;
    }
    __syncthreads();

    const int np = n >> 1;
    const int i = blockIdx.x * BLOCK + threadIdx.x;  // pair index

    float bce = 0.0f, seed_s = 0.0f, smooth_s = 0.0f;

    if (i < np) {
        const float2* e2 = (const float2*)emb;
        float2 a0 = e2[i * 3], a1 = e2[i * 3 + 1], a2 = e2[i * 3 + 2];
        float2 mg = ((const float2*)margins)[i];
        float2 sv = ((const float2*)seed)[i];
        int2 lb = ((const int2*)labels)[i];

        float x[2] = {a0.x, a1.y};
        float y[2] = {a0.y, a2.x};
        float z[2] = {a1.x, a2.y};
        float es[2], a[2] = {0.f, 0.f};
#pragma unroll
        for (int k = 0; k < 2; ++k)
            es[k] = fmaf(x[k], x[k], fmaf(y[k], y[k], z[k] * z[k]));

#pragma unroll
        for (int g = 0; g < NCLUS / 4; ++g) {
            float4 wv = s_w4[g];
            float wa[4] = {wv.x, wv.y, wv.z, wv.w};
#pragma unroll
            for (int j = 0; j < 4; ++j) {
                float4 pr = s_par[g * 4 + j];
                float w2 = wa[j];
#pragma unroll
                for (int k = 0; k < 2; ++k) {
                    float t = fmaf(pr.x, x[k], fmaf(pr.y, y[k],
                              fmaf(pr.z, z[k], fmaf(w2, es[k], pr.w))));
                    float p = EXP2F(t);
                    a[k] = fmaf(p, fmaf(p, SPQ2, SPQ1), a[k]);
                }
            }
        }
        bce += a[0] + a[1];

        float mm[2] = {mg.x, mg.y};
        float ss[2] = {sv.x, sv.y};
        int   ll[2] = {lb.x, lb.y};
#pragma unroll
        for (int k = 0; k < 2; ++k) {
            float4 pr = s_par[ll[k]];
            float w2 = ((const float*)s_w4)[ll[k]];
            float t = fmaf(pr.x, x[k], fmaf(pr.y, y[k],
                      fmaf(pr.z, z[k], fmaf(w2, es[k], pr.w))));
            float p = EXP2F(t);
            bce -= p;
            seed_s += fabsf(p - ss[k]);
            float dg = mm[k] - s_sig[ll[k]];
            smooth_s += dg * dg;
        }
    }
    // odd-n tail
    if ((n & 1) && blockIdx.x == 0 && threadIdx.x == 0) {
        int p = n - 1;
        float ex = emb[p * 3 + 0], ey = emb[p * 3 + 1], ez = emb[p * 3 + 2];
        float esq = fmaf(ex, ex, fmaf(ey, ey, ez * ez));
        int lab = labels[p];
        float pl = 0.0f;
        for (int c = 0; c < NCLUS; ++c) {
            float4 pr = s_par[c];
            float w2 = ((const float*)s_w4)[c];
            float t = fmaf(pr.x, ex, fmaf(pr.y, ey, fmaf(pr.z, ez, fmaf(w2, esq, pr.w))));
            float p2 = EXP2F(t);
            pl = (c == lab) ? p2 : pl;
            bce = fmaf(p2, fmaf(p2, SPQ2, SPQ1), bce);
        }
        bce -= pl;
        seed_s += fabsf(pl - seed[p]);
        float dg = margins[p] - s_sig[lab];
        smooth_s += dg * dg;
    }

    float r;
    r = block_reduce_f(bce, s_red);
    if (threadIdx.x == 0) pb[blockIdx.x * 3 + 0] = r;
    r = block_reduce_f(seed_s, s_red);
    if (threadIdx.x == 0) pb[blockIdx.x * 3 + 1] = r;
    r = block_reduce_f(smooth_s, s_red);
    if (threadIdx.x == 0) pb[blockIdx.x * 3 + 2] = r;
}

__global__ void finalize_kernel(const float* __restrict__ pb, int nb,
                                float* __restrict__ out, int n) {
    __shared__ float s_red[BLOCK / 64];
    float v0 = 0.f, v1 = 0.f, v2 = 0.f;
    for (int j = threadIdx.x; j < nb; j += BLOCK) {
        v0 += pb[j * 3 + 0];
        v1 += pb[j * 3 + 1];
        v2 += pb[j * 3 + 2];
    }
    float t0 = block_reduce_f(v0, s_red);
    __syncthreads();
    float t1 = block_reduce_f(v1, s_red);
    __syncthreads();
    float t2 = block_reduce_f(v2, s_red);
    if (threadIdx.x == 0) {
        double bce_total = (double)t0 + (double)n * 64.0 * SPQ0;
        out[0] = (float)(bce_total / ((double)NCLUS * (double)n)
                         + (double)t1 / (double)n + (double)t2 / (double)NCLUS);
    }
}

extern "C" void kernel_launch(void* const* d_in, const int* in_sizes, int n_in,
                              void* d_out, int out_size, void* d_ws, size_t ws_size,
                              hipStream_t stream) {
    const float* emb     = (const float*)d_in[0];
    const float* margins = (const float*)d_in[1];
    const float* seed    = (const float*)d_in[2];
    const float* coords  = (const float*)d_in[3];
    const int*   labels  = (const int*)d_in[4];
    int n = in_sizes[4];

    unsigned long long* S8 = (unsigned long long*)d_ws;
    float* pb = (float*)((char*)d_ws + 24576);
    float* out = (float*)d_out;

    int np = n >> 1;
    int grid_main = (np + BLOCK - 1) / BLOCK;
    if (grid_main < 1) grid_main = 1;
    int grid_cs = grid_main < GC ? grid_main : GC;

    init_ws_kernel<<<(NREP * 5 * NCLUS + 255) / 256, 256, 0, stream>>>(S8);
    cluster_sums_kernel<<<grid_cs, BLOCK, 0, stream>>>(coords, margins, labels, n, S8);
    main_loss_kernel<<<grid_main, BLOCK, 0, stream>>>(emb, margins, seed, labels, n, S8, pb);
    finalize_kernel<<<1, BLOCK, 0, stream>>>(pb, grid_main, out, n);
}